// Round 8
// baseline (196.162 us; speedup 1.0000x reference)
//
#include <hip/hip_runtime.h>

// GPT2 attention w/ soft-threshold pruning — round 8.
// attn: 128-thr blocks = 2 waves split-K (wave w does kvb%2==w), private
// online-softmax state, exact LDS merge at end; K prefetched one step ahead.
// GEMM1 V-epilogue writes V transposed directly (vtrans kernel removed);
// suffix-sum prep fused into one kernel.

#define S_LEN 2048
#define DM    1024
#define NH    16
#define HD    64
#define NQKV  3072
#define SLOPE 10.0f
#define CMASK -10000.0f

typedef short s16x4 __attribute__((ext_vector_type(4)));
typedef short s16x8 __attribute__((ext_vector_type(8)));
typedef float f32x4 __attribute__((ext_vector_type(4)));

#define MFMA16(a,b,c) __builtin_amdgcn_mfma_f32_16x16x32_bf16(a,b,c,0,0,0)
#define GLDS16(g,l) __builtin_amdgcn_global_load_lds( \
    (const __attribute__((address_space(1))) void*)(g), \
    (__attribute__((address_space(3))) void*)(l), 16, 0, 0)

__device__ __forceinline__ short f2bf(float f){
    unsigned u = __float_as_uint(f);
    u += 0x7fffu + ((u >> 16) & 1u);          // RNE
    return (short)(u >> 16);
}
__device__ __forceinline__ float bf2f(short x){
    return __uint_as_float(((unsigned)(unsigned short)x) << 16);
}
struct bfpair { short hi, lo; };
__device__ __forceinline__ bfpair split_bf(float x){
    bfpair r; r.hi = f2bf(x);
    r.lo = f2bf(x - bf2f(r.hi));
    return r;
}

// ---- GEMM staging: [ROWS][64] bf16 tile via global_load_lds, XOR-swizzled ----
template<int ROWS, int THREADS>
__device__ __forceinline__ void stage_tile(const short* gbase, int rstride,
                                           short* lds, int tid){
#pragma unroll
    for (int it = 0; it < ROWS*8/THREADS; ++it){
        int s = it*THREADS + tid;
        int row = s >> 3, grp = s & 7;
        const short* src = gbase + (size_t)row*rstride + ((grp ^ (row & 7)) << 3);
        GLDS16(src, lds + (size_t)s*8);
    }
}
__device__ __forceinline__ s16x8 frag(const short* lds, int row, int kg){
    return *(const s16x8*)&lds[row*64 + ((kg ^ (row & 7)) << 3)];
}

// ---------------- GEMM 128x128, BK=64, 4 waves (2x2 of 64x64) ----------------
// QKV epilogue: q split hi/lo; k bf16; v written TRANSPOSED into Vt[d][s].
template<bool WSPLIT, bool QKV>
__global__ __launch_bounds__(256)
void gemm_kern(const short* __restrict__ Ahg, const short* __restrict__ Alg,
               const short* __restrict__ Bhg, const short* __restrict__ Blg,
               const float* __restrict__ bias,
               short* __restrict__ o0h, short* __restrict__ o0l,
               short* __restrict__ o1h,
               short* __restrict__ oVt, float* __restrict__ oproj)
{
    __shared__ __align__(16) short Ah_s[128*64];
    __shared__ __align__(16) short Al_s[128*64];
    __shared__ __align__(16) short Bh_s[128*64];
    __shared__ __align__(16) short Bl_s[WSPLIT ? 128*64 : 8];

    const int tid = threadIdx.x, lane = tid & 63, wid = tid >> 6;
    const int lr = lane & 15, lg = lane >> 4;
    const int brow = blockIdx.y*128, bcol = blockIdx.x*128;
    const int wm = (wid >> 1)*64, wn = (wid & 1)*64;

    f32x4 acc[4][4];
#pragma unroll
    for (int m = 0; m < 4; ++m)
#pragma unroll
        for (int n = 0; n < 4; ++n) acc[m][n] = (f32x4){0.f,0.f,0.f,0.f};

    for (int k0 = 0; k0 < DM; k0 += 64){
        stage_tile<128,256>(Ahg + (size_t)brow*DM + k0, DM, Ah_s, tid);
        stage_tile<128,256>(Alg + (size_t)brow*DM + k0, DM, Al_s, tid);
        stage_tile<128,256>(Bhg + (size_t)bcol*DM + k0, DM, Bh_s, tid);
        if constexpr (WSPLIT)
            stage_tile<128,256>(Blg + (size_t)bcol*DM + k0, DM, Bl_s, tid);
        __syncthreads();
#pragma unroll
        for (int kc = 0; kc < 2; ++kc){
            s16x8 ah[4], al[4], bh[4], bl[4];
#pragma unroll
            for (int m = 0; m < 4; ++m){
                ah[m] = frag(Ah_s, wm + m*16 + lr, kc*4 + lg);
                al[m] = frag(Al_s, wm + m*16 + lr, kc*4 + lg);
            }
#pragma unroll
            for (int n = 0; n < 4; ++n){
                bh[n] = frag(Bh_s, wn + n*16 + lr, kc*4 + lg);
                if constexpr (WSPLIT)
                    bl[n] = frag(Bl_s, wn + n*16 + lr, kc*4 + lg);
            }
#pragma unroll
            for (int m = 0; m < 4; ++m)
#pragma unroll
                for (int n = 0; n < 4; ++n){
                    acc[m][n] = MFMA16(ah[m], bh[n], acc[m][n]);
                    if constexpr (WSPLIT)
                        acc[m][n] = MFMA16(ah[m], bl[n], acc[m][n]);
                    acc[m][n] = MFMA16(al[m], bh[n], acc[m][n]);
                }
        }
        __syncthreads();
    }

    const int sec = bcol >> 10;     // block-uniform: 0=q 1=k 2=v (QKV only)
#pragma unroll
    for (int m = 0; m < 4; ++m)
#pragma unroll
        for (int n = 0; n < 4; ++n){
            int row  = brow + wm + m*16 + lg*4;
            int gcol = bcol + wn + n*16 + lr;
            float bv = bias[gcol];
            if (QKV && sec == 2){
                // V transposed: Vt[d][s], 4 contiguous s per lane
                int col1 = gcol & 1023;
                s16x4 vv;
#pragma unroll
                for (int v = 0; v < 4; ++v) vv[v] = f2bf(acc[m][n][v] + bv);
                *(s16x4*)&oVt[(size_t)col1*S_LEN + row] = vv;
            } else {
#pragma unroll
                for (int v = 0; v < 4; ++v){
                    float val = acc[m][n][v] + bv;
                    if constexpr (QKV){
                        int col1 = gcol & 1023;
                        size_t o = (size_t)(row + v)*DM + col1;
                        if (sec == 0){ bfpair p = split_bf(val); o0h[o] = p.hi; o0l[o] = p.lo; }
                        else { o1h[o] = f2bf(val); }
                    } else {
                        oproj[(size_t)(row + v)*DM + gcol] = val;
                    }
                }
            }
        }
}

// ---------------- prep kernels ----------------
__global__ __launch_bounds__(256)
void split_f32(const float* __restrict__ x, short* __restrict__ h,
               short* __restrict__ l, int n4)
{
    int i = blockIdx.x*256 + threadIdx.x;
    if (i >= n4) return;
    float4 v = *(const float4*)&x[(size_t)i*4];
    bfpair a = split_bf(v.x), b = split_bf(v.y), c = split_bf(v.z), d = split_bf(v.w);
    s16x4 hv, lv;
    hv.x = a.hi; hv.y = b.hi; hv.z = c.hi; hv.w = d.hi;
    lv.x = a.lo; lv.y = b.lo; lv.z = c.lo; lv.w = d.lo;
    *(s16x4*)&h[(size_t)i*4] = hv;
    *(s16x4*)&l[(size_t)i*4] = lv;
}

template<bool SPL>
__global__ __launch_bounds__(256)
void wtrans(const float* __restrict__ W, int N, short* __restrict__ Th,
            short* __restrict__ Tl)
{
    __shared__ float t[64][65];
    const int tid = threadIdx.x;
    const int tn = blockIdx.x*64, tk = blockIdx.y*64;
#pragma unroll
    for (int it = 0; it < 4; ++it){
        int idx = tid + it*256;
        int r = idx >> 4, c4 = (idx & 15)*4;
        float4 v = *(const float4*)&W[(size_t)(tk + r)*N + tn + c4];
        t[r][c4] = v.x; t[r][c4+1] = v.y; t[r][c4+2] = v.z; t[r][c4+3] = v.w;
    }
    __syncthreads();
#pragma unroll
    for (int it = 0; it < 4; ++it){
        int idx = tid + it*256;
        int n = idx >> 4, c4 = (idx & 15)*4;
        s16x4 hv, lv;
#pragma unroll
        for (int j = 0; j < 4; ++j){
            bfpair p = split_bf(t[c4+j][n]);
            hv[j] = p.hi; lv[j] = p.lo;
        }
        *(s16x4*)&Th[(size_t)(tn + n)*DM + tk + c4] = hv;
        if constexpr (SPL) *(s16x4*)&Tl[(size_t)(tn + n)*DM + tk + c4] = lv;
    }
}

// per-head suffix sums of V rows (reads Vt[d][s]); SSV[h][b][d], b=0..32
__global__ __launch_bounds__(64)
void sv_kern(const short* __restrict__ Vt, float* __restrict__ SSV)
{
    int h = blockIdx.x, d = threadIdx.x;
    const short* row = Vt + (size_t)(h*HD + d)*S_LEN;
    float s = 0.f;
    SSV[((size_t)h*33 + 32)*64 + d] = 0.f;
    for (int b = 31; b >= 0; --b){
        float bs = 0.f;
#pragma unroll 8
        for (int k = 0; k < 64; ++k) bs += bf2f(row[b*64 + k]);
        s += bs;
        SSV[((size_t)h*33 + b)*64 + d] = s;
    }
}

// ---------------- Flash attention: 2-wave split-K blocks ----------------
__global__ __launch_bounds__(128)
void attn_fwd(const short* __restrict__ Qh, const short* __restrict__ Ql,
              const short* __restrict__ Kh, const short* __restrict__ Vt,
              const float* __restrict__ SSV,
              short* __restrict__ Oh, short* __restrict__ Ol)
{
    __shared__ __align__(16) short Ps[2][16*72];
    __shared__ float mrg[64][26];

    const int id = blockIdx.x;                     // 0..2047
    const int h  = (id & 7) + 8*((id >> 3) & 1);   // heads pinned per XCD
    const int qt = 127 - (id >> 4);                // descending diag = LPT
    const int diag = qt >> 2;

    const int tid = threadIdx.x, lane = tid & 63, wid = tid >> 6;  // wid 0..1
    const int lr = lane & 15, lg = lane >> 4;
    const int qrow = qt*16 + lg*4;

    const short* qbh = Qh + (size_t)(qt*16)*DM + h*HD;
    const short* qbl = Ql + (size_t)(qt*16)*DM + h*HD;
    s16x8 aqh[2], aql[2];
#pragma unroll
    for (int kc = 0; kc < 2; ++kc){
        aqh[kc] = *(const s16x8*)&qbh[(size_t)lr*DM + kc*32 + lg*8];
        aql[kc] = *(const s16x8*)&qbl[(size_t)lr*DM + kc*32 + lg*8];
    }

    float m_run[4], l_run[4];
    f32x4 acc_o[4];
#pragma unroll
    for (int v = 0; v < 4; ++v){ m_run[v] = -1e30f; l_run[v] = 0.f; }
#pragma unroll
    for (int n = 0; n < 4; ++n) acc_o[n] = (f32x4){0.f,0.f,0.f,0.f};

    const short* kb0 = Kh + (size_t)h*HD;
    const short* vb0 = Vt + (size_t)(h*HD)*S_LEN;

    // prologue: current K fragments for this wave's first kv-block
    s16x8 bkc[2][4];
    if (wid <= diag){
        const short* kb = kb0 + (size_t)(wid*64)*DM;
#pragma unroll
        for (int kc = 0; kc < 2; ++kc)
#pragma unroll
            for (int n = 0; n < 4; ++n)
                bkc[kc][n] = *(const s16x8*)&kb[(size_t)(n*16 + lr)*DM + kc*32 + lg*8];
    }

    for (int kvb = wid; kvb <= diag; kvb += 2){
        // prefetch next K (stride 2) — issues before softmax, hides latency
        s16x8 bkn[2][4];
        if (kvb + 2 <= diag){
            const short* kb = kb0 + (size_t)((kvb+2)*64)*DM;
#pragma unroll
            for (int kc = 0; kc < 2; ++kc)
#pragma unroll
                for (int n = 0; n < 4; ++n)
                    bkn[kc][n] = *(const s16x8*)&kb[(size_t)(n*16 + lr)*DM + kc*32 + lg*8];
        }

        f32x4 sc[4];
#pragma unroll
        for (int n = 0; n < 4; ++n) sc[n] = (f32x4){0.f,0.f,0.f,0.f};
#pragma unroll
        for (int kc = 0; kc < 2; ++kc)
#pragma unroll
            for (int n = 0; n < 4; ++n){
                sc[n] = MFMA16(aqh[kc], bkc[kc][n], sc[n]);
                sc[n] = MFMA16(aql[kc], bkc[kc][n], sc[n]);
            }

        // V fragment loads; latency hides under softmax VALU
        const short* vb = vb0 + kvb*64;
        s16x8 bv0[4], bv1[4];
#pragma unroll
        for (int n = 0; n < 4; ++n){
            bv0[n] = *(const s16x8*)&vb[(size_t)(16*n + lr)*S_LEN + lg*8];
            bv1[n] = *(const s16x8*)&vb[(size_t)(16*n + lr)*S_LEN + 32 + lg*8];
        }

        // soft-threshold (+ causal mask only in the diagonal block)
        float p[4][4], tmax[4];
#pragma unroll
        for (int v = 0; v < 4; ++v) tmax[v] = -1e30f;
        if (kvb == diag){
#pragma unroll
            for (int n = 0; n < 4; ++n){
                int key = kvb*64 + n*16 + lr;
#pragma unroll
                for (int v = 0; v < 4; ++v){
                    float w;
                    if (key > qrow + v) w = CMASK;
                    else {
                        float sv = sc[n][v];
                        float sig = 1.f / (1.f + __expf(-SLOPE*sv));
                        w = CMASK + (sv - CMASK)*sig;
                    }
                    p[n][v] = w;
                    tmax[v] = fmaxf(tmax[v], w);
                }
            }
        } else {
#pragma unroll
            for (int n = 0; n < 4; ++n)
#pragma unroll
                for (int v = 0; v < 4; ++v){
                    float sv = sc[n][v];
                    float sig = 1.f / (1.f + __expf(-SLOPE*sv));
                    float w = CMASK + (sv - CMASK)*sig;
                    p[n][v] = w;
                    tmax[v] = fmaxf(tmax[v], w);
                }
        }
#pragma unroll
        for (int v = 0; v < 4; ++v)
#pragma unroll
            for (int msk = 1; msk < 16; msk <<= 1)
                tmax[v] = fmaxf(tmax[v], __shfl_xor(tmax[v], msk, 64));

        float scale[4], rsum[4];
#pragma unroll
        for (int v = 0; v < 4; ++v){
            float mn = fmaxf(m_run[v], tmax[v]);
            scale[v] = __expf(m_run[v] - mn);
            m_run[v] = mn;
            rsum[v] = 0.f;
        }
#pragma unroll
        for (int n = 0; n < 4; ++n)
#pragma unroll
            for (int v = 0; v < 4; ++v){
                float e = __expf(p[n][v] - m_run[v]);
                p[n][v] = e;
                rsum[v] += e;
            }
#pragma unroll
        for (int v = 0; v < 4; ++v){
#pragma unroll
            for (int msk = 1; msk < 16; msk <<= 1)
                rsum[v] += __shfl_xor(rsum[v], msk, 64);
            l_run[v] = l_run[v]*scale[v] + rsum[v];
        }
#pragma unroll
        for (int n = 0; n < 4; ++n)
#pragma unroll
            for (int v = 0; v < 4; ++v) acc_o[n][v] *= scale[v];

        // P (D-layout) -> per-wave LDS -> A-frag layout
#pragma unroll
        for (int n = 0; n < 4; ++n)
#pragma unroll
            for (int v = 0; v < 4; ++v)
                Ps[wid][(lg*4 + v)*72 + 16*n + lr] = f2bf(p[n][v]);
        asm volatile("s_waitcnt lgkmcnt(0)" ::: "memory");

        s16x8 pa0 = *(const s16x8*)&Ps[wid][lr*72 + lg*8];
        s16x8 pa1 = *(const s16x8*)&Ps[wid][lr*72 + 32 + lg*8];
#pragma unroll
        for (int n = 0; n < 4; ++n){
            acc_o[n] = MFMA16(pa0, bv0[n], acc_o[n]);
            acc_o[n] = MFMA16(pa1, bv1[n], acc_o[n]);
        }

        // rotate prefetched K
#pragma unroll
        for (int kc = 0; kc < 2; ++kc)
#pragma unroll
            for (int n = 0; n < 4; ++n) bkc[kc][n] = bkn[kc][n];
    }

    // ---- split-K merge: wave1 publishes, wave0 merges ----
    if (wid == 1){
#pragma unroll
        for (int v = 0; v < 4; ++v){
            mrg[lane][v] = m_run[v];
            mrg[lane][4 + v] = l_run[v];
        }
#pragma unroll
        for (int n = 0; n < 4; ++n)
#pragma unroll
            for (int v = 0; v < 4; ++v) mrg[lane][8 + n*4 + v] = acc_o[n][v];
    }
    __syncthreads();
    if (wid != 0) return;

    float e0[4];
#pragma unroll
    for (int v = 0; v < 4; ++v){
        float m1 = mrg[lane][v], l1 = mrg[lane][4 + v];
        float mn = fmaxf(m_run[v], m1);
        e0[v] = __expf(m_run[v] - mn);
        float e1 = __expf(m1 - mn);
        l_run[v] = l_run[v]*e0[v] + l1*e1;
        m_run[v] = mn;
        mrg[lane][4 + v] = e1;          // reuse slot for factor
    }
#pragma unroll
    for (int n = 0; n < 4; ++n)
#pragma unroll
        for (int v = 0; v < 4; ++v)
            acc_o[n][v] = acc_o[n][v]*e0[v] + mrg[lane][8 + n*4 + v]*mrg[lane][4 + v];

    // analytic masked-future tail: every future key has weight exp(CMASK - m)
    {
        const float* sv = SSV + ((size_t)h*33 + (diag + 1))*64;
        float F = (float)(S_LEN - 64*(diag + 1));
        float e[4];
#pragma unroll
        for (int v = 0; v < 4; ++v){
            e[v] = __expf(CMASK - m_run[v]);
            l_run[v] += e[v]*F;
        }
#pragma unroll
        for (int n = 0; n < 4; ++n){
            float svv = sv[16*n + lr];
#pragma unroll
            for (int v = 0; v < 4; ++v) acc_o[n][v] += e[v]*svv;
        }
    }

    // normalize + split-store bf16 hi/lo
#pragma unroll
    for (int n = 0; n < 4; ++n)
#pragma unroll
        for (int v = 0; v < 4; ++v){
            int row = qt*16 + lg*4 + v;
            int col = h*HD + 16*n + lr;
            bfpair p = split_bf(acc_o[n][v] / l_run[v]);
            Oh[(size_t)row*DM + col] = p.hi;
            Ol[(size_t)row*DM + col] = p.lo;
        }
}

extern "C" void kernel_launch(void* const* d_in, const int* in_sizes, int n_in,
                              void* d_out, int out_size, void* d_ws, size_t ws_size,
                              hipStream_t stream)
{
    (void)in_sizes; (void)n_in; (void)out_size; (void)ws_size;
    const float* hs   = (const float*)d_in[0];
    const float* wqkv = (const float*)d_in[1];
    const float* bqkv = (const float*)d_in[2];
    const float* wprj = (const float*)d_in[3];
    const float* bprj = (const float*)d_in[4];

    char* p = (char*)d_ws;                       // ~41.2 MiB used
    short* Ahg  = (short*)(p + (0ull  << 20));   // 4 MiB  (later: Oh)
    short* Alg  = (short*)(p + (4ull  << 20));   // 4 MiB  (later: Ol)
    short* WqTh = (short*)(p + (8ull  << 20));   // 6 MiB  (later: WprojT)
    short* WqTl = (short*)(p + (14ull << 20));   // 6 MiB
    short* Qhg  = (short*)(p + (20ull << 20));   // 4 MiB
    short* Qlg  = (short*)(p + (24ull << 20));
    short* Khg  = (short*)(p + (28ull << 20));
    short* Vtg  = (short*)(p + (32ull << 20));
    float* PB   = (float*)(p + (36ull << 20));   // (unused slot kept)
    float* SSV  = (float*)(p + (37ull << 20));   // 132 KiB
    short* Oh = Ahg, * Ol = Alg;                 // reuse after GEMM1
    short* WpT = WqTh;                           // reuse after GEMM1
    (void)PB;

    split_f32<<<S_LEN*DM/4/256, 256, 0, stream>>>(hs, Ahg, Alg, S_LEN*DM/4);
    wtrans<true><<<dim3(NQKV/64, DM/64), 256, 0, stream>>>(wqkv, NQKV, WqTh, WqTl);

    gemm_kern<true, true><<<dim3(NQKV/128, S_LEN/128), 256, 0, stream>>>(
        Ahg, Alg, WqTh, WqTl, bqkv, Qhg, Qlg, Khg, Vtg, nullptr);

    wtrans<false><<<dim3(DM/64, DM/64), 256, 0, stream>>>(wprj, DM, WpT, nullptr);
    sv_kern<<<NH, 64, 0, stream>>>(Vtg, SSV);

    attn_fwd<<<2048, 128, 0, stream>>>(Qhg, Qlg, Khg, Vtg, SSV, Oh, Ol);

    gemm_kern<false, false><<<dim3(DM/128, S_LEN/128), 256, 0, stream>>>(
        Oh, Ol, WpT, nullptr, bprj, nullptr, nullptr, nullptr, nullptr,
        (float*)d_out);
}

// Round 9
// 169.785 us; speedup vs baseline: 1.1554x; 1.1554x over previous
//
#include <hip/hip_runtime.h>

// GPT2 attention w/ soft-threshold pruning — round 9.
// vs r8: (1) REVERT GEMM1 V-scatter epilogue + serial sv_kern (regressions:
// uncoalesced 8B/4KB-stride writes; 16-block serial reduce) back to r7's
// row-major V + vtrans + sv_partial/sv_suffix. (2) attn: 4-wave (256-thr)
// split-K blocks (wave w does kvb%4==w, private online state, exact 4-way
// LDS merge) -> 4x wave supply, heavy-job serial length 16 -> 8 iters.

#define S_LEN 2048
#define DM    1024
#define NH    16
#define HD    64
#define NQKV  3072
#define SLOPE 10.0f
#define CMASK -10000.0f

typedef short s16x4 __attribute__((ext_vector_type(4)));
typedef short s16x8 __attribute__((ext_vector_type(8)));
typedef float f32x4 __attribute__((ext_vector_type(4)));

#define MFMA16(a,b,c) __builtin_amdgcn_mfma_f32_16x16x32_bf16(a,b,c,0,0,0)
#define GLDS16(g,l) __builtin_amdgcn_global_load_lds( \
    (const __attribute__((address_space(1))) void*)(g), \
    (__attribute__((address_space(3))) void*)(l), 16, 0, 0)

__device__ __forceinline__ short f2bf(float f){
    unsigned u = __float_as_uint(f);
    u += 0x7fffu + ((u >> 16) & 1u);          // RNE
    return (short)(u >> 16);
}
__device__ __forceinline__ float bf2f(short x){
    return __uint_as_float(((unsigned)(unsigned short)x) << 16);
}
struct bfpair { short hi, lo; };
__device__ __forceinline__ bfpair split_bf(float x){
    bfpair r; r.hi = f2bf(x);
    r.lo = f2bf(x - bf2f(r.hi));
    return r;
}

// ---- GEMM staging: [ROWS][64] bf16 tile via global_load_lds, XOR-swizzled ----
template<int ROWS, int THREADS>
__device__ __forceinline__ void stage_tile(const short* gbase, int rstride,
                                           short* lds, int tid){
#pragma unroll
    for (int it = 0; it < ROWS*8/THREADS; ++it){
        int s = it*THREADS + tid;
        int row = s >> 3, grp = s & 7;
        const short* src = gbase + (size_t)row*rstride + ((grp ^ (row & 7)) << 3);
        GLDS16(src, lds + (size_t)s*8);
    }
}
__device__ __forceinline__ s16x8 frag(const short* lds, int row, int kg){
    return *(const s16x8*)&lds[row*64 + ((kg ^ (row & 7)) << 3)];
}

// ---------------- GEMM 128x128, BK=64, 4 waves (2x2 of 64x64) ----------------
template<bool WSPLIT, bool QKV>
__global__ __launch_bounds__(256)
void gemm_kern(const short* __restrict__ Ahg, const short* __restrict__ Alg,
               const short* __restrict__ Bhg, const short* __restrict__ Blg,
               const float* __restrict__ bias,
               short* __restrict__ o0h, short* __restrict__ o0l,
               short* __restrict__ o1h,
               short* __restrict__ o2,  float* __restrict__ oproj)
{
    __shared__ __align__(16) short Ah_s[128*64];
    __shared__ __align__(16) short Al_s[128*64];
    __shared__ __align__(16) short Bh_s[128*64];
    __shared__ __align__(16) short Bl_s[WSPLIT ? 128*64 : 8];

    const int tid = threadIdx.x, lane = tid & 63, wid = tid >> 6;
    const int lr = lane & 15, lg = lane >> 4;
    const int brow = blockIdx.y*128, bcol = blockIdx.x*128;
    const int wm = (wid >> 1)*64, wn = (wid & 1)*64;

    f32x4 acc[4][4];
#pragma unroll
    for (int m = 0; m < 4; ++m)
#pragma unroll
        for (int n = 0; n < 4; ++n) acc[m][n] = (f32x4){0.f,0.f,0.f,0.f};

    for (int k0 = 0; k0 < DM; k0 += 64){
        stage_tile<128,256>(Ahg + (size_t)brow*DM + k0, DM, Ah_s, tid);
        stage_tile<128,256>(Alg + (size_t)brow*DM + k0, DM, Al_s, tid);
        stage_tile<128,256>(Bhg + (size_t)bcol*DM + k0, DM, Bh_s, tid);
        if constexpr (WSPLIT)
            stage_tile<128,256>(Blg + (size_t)bcol*DM + k0, DM, Bl_s, tid);
        __syncthreads();
#pragma unroll
        for (int kc = 0; kc < 2; ++kc){
            s16x8 ah[4], al[4], bh[4], bl[4];
#pragma unroll
            for (int m = 0; m < 4; ++m){
                ah[m] = frag(Ah_s, wm + m*16 + lr, kc*4 + lg);
                al[m] = frag(Al_s, wm + m*16 + lr, kc*4 + lg);
            }
#pragma unroll
            for (int n = 0; n < 4; ++n){
                bh[n] = frag(Bh_s, wn + n*16 + lr, kc*4 + lg);
                if constexpr (WSPLIT)
                    bl[n] = frag(Bl_s, wn + n*16 + lr, kc*4 + lg);
            }
#pragma unroll
            for (int m = 0; m < 4; ++m)
#pragma unroll
                for (int n = 0; n < 4; ++n){
                    acc[m][n] = MFMA16(ah[m], bh[n], acc[m][n]);
                    if constexpr (WSPLIT)
                        acc[m][n] = MFMA16(ah[m], bl[n], acc[m][n]);
                    acc[m][n] = MFMA16(al[m], bh[n], acc[m][n]);
                }
        }
        __syncthreads();
    }

    const int sec = bcol >> 10;     // block-uniform: 0=q 1=k 2=v (QKV only)
#pragma unroll
    for (int m = 0; m < 4; ++m)
#pragma unroll
        for (int n = 0; n < 4; ++n){
            int row  = brow + wm + m*16 + lg*4;
            int gcol = bcol + wn + n*16 + lr;
            float bv = bias[gcol];
#pragma unroll
            for (int v = 0; v < 4; ++v){
                float val = acc[m][n][v] + bv;
                if constexpr (QKV){
                    int col1 = gcol & 1023;
                    size_t o = (size_t)(row + v)*DM + col1;
                    if (sec == 0){ bfpair p = split_bf(val); o0h[o] = p.hi; o0l[o] = p.lo; }
                    else if (sec == 1){ o1h[o] = f2bf(val); }
                    else { o2[o] = f2bf(val); }
                } else {
                    oproj[(size_t)(row + v)*DM + gcol] = val;
                }
            }
        }
}

// ---------------- prep kernels ----------------
__global__ __launch_bounds__(256)
void split_f32(const float* __restrict__ x, short* __restrict__ h,
               short* __restrict__ l, int n4)
{
    int i = blockIdx.x*256 + threadIdx.x;
    if (i >= n4) return;
    float4 v = *(const float4*)&x[(size_t)i*4];
    bfpair a = split_bf(v.x), b = split_bf(v.y), c = split_bf(v.z), d = split_bf(v.w);
    s16x4 hv, lv;
    hv.x = a.hi; hv.y = b.hi; hv.z = c.hi; hv.w = d.hi;
    lv.x = a.lo; lv.y = b.lo; lv.z = c.lo; lv.w = d.lo;
    *(s16x4*)&h[(size_t)i*4] = hv;
    *(s16x4*)&l[(size_t)i*4] = lv;
}

template<bool SPL>
__global__ __launch_bounds__(256)
void wtrans(const float* __restrict__ W, int N, short* __restrict__ Th,
            short* __restrict__ Tl)
{
    __shared__ float t[64][65];
    const int tid = threadIdx.x;
    const int tn = blockIdx.x*64, tk = blockIdx.y*64;
#pragma unroll
    for (int it = 0; it < 4; ++it){
        int idx = tid + it*256;
        int r = idx >> 4, c4 = (idx & 15)*4;
        float4 v = *(const float4*)&W[(size_t)(tk + r)*N + tn + c4];
        t[r][c4] = v.x; t[r][c4+1] = v.y; t[r][c4+2] = v.z; t[r][c4+3] = v.w;
    }
    __syncthreads();
#pragma unroll
    for (int it = 0; it < 4; ++it){
        int idx = tid + it*256;
        int n = idx >> 4, c4 = (idx & 15)*4;
        s16x4 hv, lv;
#pragma unroll
        for (int j = 0; j < 4; ++j){
            bfpair p = split_bf(t[c4+j][n]);
            hv[j] = p.hi; lv[j] = p.lo;
        }
        *(s16x4*)&Th[(size_t)(tn + n)*DM + tk + c4] = hv;
        if constexpr (SPL) *(s16x4*)&Tl[(size_t)(tn + n)*DM + tk + c4] = lv;
    }
}

__global__ __launch_bounds__(256)
void vtrans(const short* __restrict__ Vb, short* __restrict__ Vt)
{
    __shared__ short t[64][66];
    const int tid = threadIdx.x;
    const int td = blockIdx.x*64, ts = blockIdx.y*64;
#pragma unroll
    for (int it = 0; it < 4; ++it){
        int idx = tid + it*256;
        int r = idx >> 4, c4 = (idx & 15)*4;
        s16x4 v = *(const s16x4*)&Vb[(size_t)(ts + r)*DM + td + c4];
        t[r][c4] = v.x; t[r][c4+1] = v.y; t[r][c4+2] = v.z; t[r][c4+3] = v.w;
    }
    __syncthreads();
#pragma unroll
    for (int it = 0; it < 4; ++it){
        int idx = tid + it*256;
        int n = idx >> 4, c4 = (idx & 15)*4;
        s16x4 o;
#pragma unroll
        for (int j = 0; j < 4; ++j) o[j] = t[c4+j][n];
        *(s16x4*)&Vt[(size_t)(td + n)*S_LEN + ts + c4] = o;
    }
}

// per-64-key-block partial sums of V, then per-head suffix sums
__global__ __launch_bounds__(64)
void sv_partial(const short* __restrict__ Vb, float* __restrict__ PB)
{
    int b = blockIdx.x, h = blockIdx.y, d = threadIdx.x;
    float s = 0.f;
#pragma unroll 8
    for (int k = 0; k < 64; ++k)
        s += bf2f(Vb[(size_t)(b*64 + k)*DM + h*HD + d]);
    PB[((size_t)h*32 + b)*64 + d] = s;
}
__global__ __launch_bounds__(64)
void sv_suffix(const float* __restrict__ PB, float* __restrict__ SSV)
{
    int h = blockIdx.x, d = threadIdx.x;
    float s = 0.f;
    SSV[((size_t)h*33 + 32)*64 + d] = 0.f;
    for (int b = 31; b >= 0; --b){
        s += PB[((size_t)h*32 + b)*64 + d];
        SSV[((size_t)h*33 + b)*64 + d] = s;
    }
}

// ---------------- Flash attention: 4-wave split-K blocks ----------------
__global__ __launch_bounds__(256)
void attn_fwd(const short* __restrict__ Qh, const short* __restrict__ Ql,
              const short* __restrict__ Kh, const short* __restrict__ Vt,
              const float* __restrict__ SSV,
              short* __restrict__ Oh, short* __restrict__ Ol)
{
    __shared__ __align__(16) short Ps[4][16*72];
    __shared__ float mrg[3][64][24];     // waves 1..3: m[4], l[4], acc[16]

    const int id = blockIdx.x;                     // 0..2047
    const int h  = (id & 7) + 8*((id >> 3) & 1);   // heads pinned per XCD
    const int qt = 127 - (id >> 4);                // descending diag
    const int diag = qt >> 2;

    const int tid = threadIdx.x, lane = tid & 63, wid = tid >> 6;  // wid 0..3
    const int lr = lane & 15, lg = lane >> 4;
    const int qrow = qt*16 + lg*4;

    const short* qbh = Qh + (size_t)(qt*16)*DM + h*HD;
    const short* qbl = Ql + (size_t)(qt*16)*DM + h*HD;
    s16x8 aqh[2], aql[2];
#pragma unroll
    for (int kc = 0; kc < 2; ++kc){
        aqh[kc] = *(const s16x8*)&qbh[(size_t)lr*DM + kc*32 + lg*8];
        aql[kc] = *(const s16x8*)&qbl[(size_t)lr*DM + kc*32 + lg*8];
    }

    float m_run[4], l_run[4];
    f32x4 acc_o[4];
#pragma unroll
    for (int v = 0; v < 4; ++v){ m_run[v] = -1e30f; l_run[v] = 0.f; }
#pragma unroll
    for (int n = 0; n < 4; ++n) acc_o[n] = (f32x4){0.f,0.f,0.f,0.f};

    const short* kb0 = Kh + (size_t)h*HD;
    const short* vb0 = Vt + (size_t)(h*HD)*S_LEN;

    // prologue: this wave's first K block (kvb = wid)
    s16x8 bkc[2][4];
    if (wid <= diag){
        const short* kb = kb0 + (size_t)(wid*64)*DM;
#pragma unroll
        for (int kc = 0; kc < 2; ++kc)
#pragma unroll
            for (int n = 0; n < 4; ++n)
                bkc[kc][n] = *(const s16x8*)&kb[(size_t)(n*16 + lr)*DM + kc*32 + lg*8];
    }

    for (int kvb = wid; kvb <= diag; kvb += 4){
        // prefetch next K (stride 4) before softmax
        s16x8 bkn[2][4];
        if (kvb + 4 <= diag){
            const short* kb = kb0 + (size_t)((kvb+4)*64)*DM;
#pragma unroll
            for (int kc = 0; kc < 2; ++kc)
#pragma unroll
                for (int n = 0; n < 4; ++n)
                    bkn[kc][n] = *(const s16x8*)&kb[(size_t)(n*16 + lr)*DM + kc*32 + lg*8];
        }

        f32x4 sc[4];
#pragma unroll
        for (int n = 0; n < 4; ++n) sc[n] = (f32x4){0.f,0.f,0.f,0.f};
#pragma unroll
        for (int kc = 0; kc < 2; ++kc)
#pragma unroll
            for (int n = 0; n < 4; ++n){
                sc[n] = MFMA16(aqh[kc], bkc[kc][n], sc[n]);
                sc[n] = MFMA16(aql[kc], bkc[kc][n], sc[n]);
            }

        // V fragment loads; latency hides under softmax VALU
        const short* vb = vb0 + kvb*64;
        s16x8 bv0[4], bv1[4];
#pragma unroll
        for (int n = 0; n < 4; ++n){
            bv0[n] = *(const s16x8*)&vb[(size_t)(16*n + lr)*S_LEN + lg*8];
            bv1[n] = *(const s16x8*)&vb[(size_t)(16*n + lr)*S_LEN + 32 + lg*8];
        }

        // soft-threshold (+ causal mask only in the diagonal block)
        float p[4][4], tmax[4];
#pragma unroll
        for (int v = 0; v < 4; ++v) tmax[v] = -1e30f;
        if (kvb == diag){
#pragma unroll
            for (int n = 0; n < 4; ++n){
                int key = kvb*64 + n*16 + lr;
#pragma unroll
                for (int v = 0; v < 4; ++v){
                    float w;
                    if (key > qrow + v) w = CMASK;
                    else {
                        float sv = sc[n][v];
                        float sig = 1.f / (1.f + __expf(-SLOPE*sv));
                        w = CMASK + (sv - CMASK)*sig;
                    }
                    p[n][v] = w;
                    tmax[v] = fmaxf(tmax[v], w);
                }
            }
        } else {
#pragma unroll
            for (int n = 0; n < 4; ++n)
#pragma unroll
                for (int v = 0; v < 4; ++v){
                    float sv = sc[n][v];
                    float sig = 1.f / (1.f + __expf(-SLOPE*sv));
                    float w = CMASK + (sv - CMASK)*sig;
                    p[n][v] = w;
                    tmax[v] = fmaxf(tmax[v], w);
                }
        }
#pragma unroll
        for (int v = 0; v < 4; ++v)
#pragma unroll
            for (int msk = 1; msk < 16; msk <<= 1)
                tmax[v] = fmaxf(tmax[v], __shfl_xor(tmax[v], msk, 64));

        float scale[4], rsum[4];
#pragma unroll
        for (int v = 0; v < 4; ++v){
            float mn = fmaxf(m_run[v], tmax[v]);
            scale[v] = __expf(m_run[v] - mn);
            m_run[v] = mn;
            rsum[v] = 0.f;
        }
#pragma unroll
        for (int n = 0; n < 4; ++n)
#pragma unroll
            for (int v = 0; v < 4; ++v){
                float e = __expf(p[n][v] - m_run[v]);
                p[n][v] = e;
                rsum[v] += e;
            }
#pragma unroll
        for (int v = 0; v < 4; ++v){
#pragma unroll
            for (int msk = 1; msk < 16; msk <<= 1)
                rsum[v] += __shfl_xor(rsum[v], msk, 64);
            l_run[v] = l_run[v]*scale[v] + rsum[v];
        }
#pragma unroll
        for (int n = 0; n < 4; ++n)
#pragma unroll
            for (int v = 0; v < 4; ++v) acc_o[n][v] *= scale[v];

        // P (D-layout) -> per-wave LDS -> A-frag layout
#pragma unroll
        for (int n = 0; n < 4; ++n)
#pragma unroll
            for (int v = 0; v < 4; ++v)
                Ps[wid][(lg*4 + v)*72 + 16*n + lr] = f2bf(p[n][v]);
        asm volatile("s_waitcnt lgkmcnt(0)" ::: "memory");

        s16x8 pa0 = *(const s16x8*)&Ps[wid][lr*72 + lg*8];
        s16x8 pa1 = *(const s16x8*)&Ps[wid][lr*72 + 32 + lg*8];
#pragma unroll
        for (int n = 0; n < 4; ++n){
            acc_o[n] = MFMA16(pa0, bv0[n], acc_o[n]);
            acc_o[n] = MFMA16(pa1, bv1[n], acc_o[n]);
        }

        // rotate prefetched K
#pragma unroll
        for (int kc = 0; kc < 2; ++kc)
#pragma unroll
            for (int n = 0; n < 4; ++n) bkc[kc][n] = bkn[kc][n];
    }

    // ---- split-K merge: waves 1..3 publish, wave 0 merges ----
    if (wid != 0){
#pragma unroll
        for (int v = 0; v < 4; ++v){
            mrg[wid-1][lane][v] = m_run[v];
            mrg[wid-1][lane][4 + v] = l_run[v];
        }
#pragma unroll
        for (int n = 0; n < 4; ++n)
#pragma unroll
            for (int v = 0; v < 4; ++v) mrg[wid-1][lane][8 + n*4 + v] = acc_o[n][v];
    }
    __syncthreads();
    if (wid != 0) return;

#pragma unroll
    for (int w = 0; w < 3; ++w){
        float e0[4], e1[4];
#pragma unroll
        for (int v = 0; v < 4; ++v){
            float m1 = mrg[w][lane][v], l1 = mrg[w][lane][4 + v];
            float mn = fmaxf(m_run[v], m1);
            e0[v] = __expf(m_run[v] - mn);   // empty wave: exp(-1e30-mn)=0
            e1[v] = __expf(m1 - mn);
            l_run[v] = l_run[v]*e0[v] + l1*e1[v];
            m_run[v] = mn;
        }
#pragma unroll
        for (int n = 0; n < 4; ++n)
#pragma unroll
            for (int v = 0; v < 4; ++v)
                acc_o[n][v] = acc_o[n][v]*e0[v] + mrg[w][lane][8 + n*4 + v]*e1[v];
    }

    // analytic masked-future tail: every future key has weight exp(CMASK - m)
    {
        const float* sv = SSV + ((size_t)h*33 + (diag + 1))*64;
        float F = (float)(S_LEN - 64*(diag + 1));
        float e[4];
#pragma unroll
        for (int v = 0; v < 4; ++v){
            e[v] = __expf(CMASK - m_run[v]);
            l_run[v] += e[v]*F;
        }
#pragma unroll
        for (int n = 0; n < 4; ++n){
            float svv = sv[16*n + lr];
#pragma unroll
            for (int v = 0; v < 4; ++v) acc_o[n][v] += e[v]*svv;
        }
    }

    // normalize + split-store bf16 hi/lo
#pragma unroll
    for (int n = 0; n < 4; ++n)
#pragma unroll
        for (int v = 0; v < 4; ++v){
            int row = qt*16 + lg*4 + v;
            int col = h*HD + 16*n + lr;
            bfpair p = split_bf(acc_o[n][v] / l_run[v]);
            Oh[(size_t)row*DM + col] = p.hi;
            Ol[(size_t)row*DM + col] = p.lo;
        }
}

extern "C" void kernel_launch(void* const* d_in, const int* in_sizes, int n_in,
                              void* d_out, int out_size, void* d_ws, size_t ws_size,
                              hipStream_t stream)
{
    (void)in_sizes; (void)n_in; (void)out_size; (void)ws_size;
    const float* hs   = (const float*)d_in[0];
    const float* wqkv = (const float*)d_in[1];
    const float* bqkv = (const float*)d_in[2];
    const float* wprj = (const float*)d_in[3];
    const float* bprj = (const float*)d_in[4];

    char* p = (char*)d_ws;                       // ~45.2 MiB used
    short* Ahg  = (short*)(p + (0ull  << 20));   // 4 MiB  (later: Oh)
    short* Alg  = (short*)(p + (4ull  << 20));   // 4 MiB  (later: Ol)
    short* WqTh = (short*)(p + (8ull  << 20));   // 6 MiB  (later: WprojT)
    short* WqTl = (short*)(p + (14ull << 20));   // 6 MiB
    short* Qhg  = (short*)(p + (20ull << 20));   // 4 MiB
    short* Qlg  = (short*)(p + (24ull << 20));
    short* Khg  = (short*)(p + (28ull << 20));
    short* Vbg  = (short*)(p + (32ull << 20));
    short* Vtg  = (short*)(p + (36ull << 20));
    float* PB   = (float*)(p + (40ull << 20));   // 128 KiB
    float* SSV  = (float*)(p + (41ull << 20));   // 132 KiB
    short* Oh = Ahg, * Ol = Alg;                 // reuse after GEMM1
    short* WpT = WqTh;                           // reuse after GEMM1

    split_f32<<<S_LEN*DM/4/256, 256, 0, stream>>>(hs, Ahg, Alg, S_LEN*DM/4);
    wtrans<true><<<dim3(NQKV/64, DM/64), 256, 0, stream>>>(wqkv, NQKV, WqTh, WqTl);

    gemm_kern<true, true><<<dim3(NQKV/128, S_LEN/128), 256, 0, stream>>>(
        Ahg, Alg, WqTh, WqTl, bqkv, Qhg, Qlg, Khg, Vbg, nullptr);

    wtrans<false><<<dim3(DM/64, DM/64), 256, 0, stream>>>(wprj, DM, WpT, nullptr);
    vtrans<<<dim3(DM/64, S_LEN/64), 256, 0, stream>>>(Vbg, Vtg);
    sv_partial<<<dim3(32, NH), 64, 0, stream>>>(Vbg, PB);
    sv_suffix<<<NH, 64, 0, stream>>>(PB, SSV);

    attn_fwd<<<2048, 256, 0, stream>>>(Qhg, Qlg, Khg, Vtg, SSV, Oh, Ol);

    gemm_kern<false, false><<<dim3(DM/128, S_LEN/128), 256, 0, stream>>>(
        Oh, Ol, WpT, nullptr, bprj, nullptr, nullptr, nullptr, nullptr,
        (float*)d_out);
}